// Round 1
// baseline (4022.841 us; speedup 1.0000x reference)
//
#include <hip/hip_runtime.h>
#include <math.h>

#define N 4096
#define DIM 64
#define MAX_ITER 50
#define EPS 0.1f
#define INV_EPS 10.0f
#define THRESH 0.1f

// persistent-kernel geometry: 1024 blocks x 256 threads, 4 blocks/CU co-resident
#define NBLK 1024
#define RPB 4              // rows per block
#define NGRP 32            // barrier groups
#define GRP_SZ (NBLK / NGRP)

// ws layout (floats). ~35 KB total.
#define WS_ERR  (2 * N)            // err[MAX_ITER]
#define WS_COST (2 * N + 50)       // cost accumulator
#define WS_GEN  (2 * N + 64)       // barrier generation (own cache line)
#define WS_ROOT (2 * N + 80)       // barrier root counter (own cache line)
#define WS_L1   (2 * N + 96)       // 32 group counters, 64B stride
#define WS_TOTAL (2 * N + 96 + NGRP * 16)

// ---------------- init: zero u, v, err, cost, barrier counters ----------------
__global__ void init_ws(float* __restrict__ ws) {
    int i = blockIdx.x * 256 + threadIdx.x;
    if (i < WS_TOTAL) ws[i] = 0.0f;
}

// ---------------- build D[i][j] = sum_d (A[i][d]-B[j][d])^2 ----------------
// grid (64,64), block 256. 64x64 tile per block, 4x4 micro-tile per thread.
__global__ __launch_bounds__(256) void build_dist(const float* __restrict__ A,
                                                  const float* __restrict__ B,
                                                  float* __restrict__ Dst) {
    __shared__ float As[64][68];
    __shared__ float Bs[64][68];
    const int i0 = blockIdx.y << 6, j0 = blockIdx.x << 6;
    const int t = threadIdx.x;
    const float* Ag = A + (size_t)i0 * DIM;
    const float* Bg = B + (size_t)j0 * DIM;
    for (int k = t; k < 4096; k += 256) {
        As[k >> 6][k & 63] = Ag[k];
        Bs[k >> 6][k & 63] = Bg[k];
    }
    __syncthreads();
    const int ty = t >> 4, tx = t & 15;
    float acc[4][4] = {{0.f}};
    for (int d = 0; d < DIM; d += 4) {
        float4 av[4], bv[4];
#pragma unroll
        for (int a = 0; a < 4; ++a) av[a] = *(const float4*)&As[ty + 16 * a][d];
#pragma unroll
        for (int b = 0; b < 4; ++b) bv[b] = *(const float4*)&Bs[tx + 16 * b][d];
#pragma unroll
        for (int a = 0; a < 4; ++a)
#pragma unroll
            for (int b = 0; b < 4; ++b) {
                float d0 = av[a].x - bv[b].x;
                float d1 = av[a].y - bv[b].y;
                float d2 = av[a].z - bv[b].z;
                float d3 = av[a].w - bv[b].w;
                acc[a][b] = fmaf(d0, d0, acc[a][b]);
                acc[a][b] = fmaf(d1, d1, acc[a][b]);
                acc[a][b] = fmaf(d2, d2, acc[a][b]);
                acc[a][b] = fmaf(d3, d3, acc[a][b]);
            }
    }
#pragma unroll
    for (int a = 0; a < 4; ++a) {
        int i = i0 + ty + 16 * a;
        float* drow = Dst + (size_t)i * N + j0;
#pragma unroll
        for (int b = 0; b < 4; ++b) drow[tx + 16 * b] = acc[a][b];
    }
}

// ---------------- software grid barrier (two-level, monotone, no resets) -------
// All 1024 blocks are co-resident by construction (launch_bounds caps VGPR at
// 128 -> 4 blocks/CU x 256 CUs == grid). Agent-scope acq_rel atomics give
// cross-XCD visibility (L2 wb on release, inv on acquire) per Guideline 16.
__device__ __forceinline__ void grid_sync(float* ws, int b) {
    __syncthreads();  // drains this block's stores to L2 (vmcnt(0) before s_barrier)
    if (threadIdx.x == 0) {
        unsigned* gen  = (unsigned*)(ws + WS_GEN);
        unsigned* root = (unsigned*)(ws + WS_ROOT);
        unsigned* l1   = (unsigned*)(ws + WS_L1) + (size_t)(b & (NGRP - 1)) * 16;
        unsigned old1 = __hip_atomic_fetch_add(l1, 1u, __ATOMIC_ACQ_REL,
                                               __HIP_MEMORY_SCOPE_AGENT);
        unsigned target = old1 / GRP_SZ + 1u;      // barrier index + 1
        if ((old1 % GRP_SZ) == GRP_SZ - 1u) {      // last of group -> arrive at root
            unsigned old0 = __hip_atomic_fetch_add(root, 1u, __ATOMIC_ACQ_REL,
                                                   __HIP_MEMORY_SCOPE_AGENT);
            if ((old0 % NGRP) == NGRP - 1u)        // last group -> release new gen
                __hip_atomic_store(gen, old0 / NGRP + 1u, __ATOMIC_RELEASE,
                                   __HIP_MEMORY_SCOPE_AGENT);
        }
        while (__hip_atomic_load(gen, __ATOMIC_RELAXED, __HIP_MEMORY_SCOPE_AGENT) <
               target)
            __builtin_amdgcn_s_sleep(8);
        __builtin_amdgcn_fence(__ATOMIC_ACQUIRE, "agent");  // invalidate L1/L2
    }
    __syncthreads();
}

// ---------------- one Sinkhorn half-step for 4 rows, in-kernel ----------------
// new_i = target - max_j(o_j - M_ij) - EPS*log(sum_j exp((d_j - dmax)*INV_EPS))
template <bool WRITE_ERR>
__device__ __forceinline__ void half_step(const float* __restrict__ Mtx,
                                          const float* __restrict__ other,
                                          float* __restrict__ mine,
                                          float* __restrict__ errslot, int r0,
                                          int t, float target, float* red) {
    float4 V[4];
    const float4* vv = (const float4*)other;
#pragma unroll
    for (int k = 0; k < 4; ++k) V[k] = vv[t + 256 * k];
    // prefetch all 4 rows (16 x 16B loads in flight -> MLP hides L3 latency)
    float4 Cr[RPB][4];
#pragma unroll
    for (int r = 0; r < RPB; ++r) {
        const float4* row = (const float4*)(Mtx + (size_t)(r0 + r) * N);
#pragma unroll
        for (int k = 0; k < 4; ++k) Cr[r][k] = row[t + 256 * k];
    }
    float nv[RPB];
#pragma unroll
    for (int r = 0; r < RPB; ++r) {
        float m = -1e30f;
#pragma unroll
        for (int k = 0; k < 4; ++k)
            m = fmaxf(m, fmaxf(fmaxf(V[k].x - Cr[r][k].x, V[k].y - Cr[r][k].y),
                               fmaxf(V[k].z - Cr[r][k].z, V[k].w - Cr[r][k].w)));
#pragma unroll
        for (int off = 32; off; off >>= 1) m = fmaxf(m, __shfl_xor(m, off));
        if ((t & 63) == 0) red[t >> 6] = m;
        __syncthreads();
        m = fmaxf(fmaxf(red[0], red[1]), fmaxf(red[2], red[3]));
        float s = 0.f;
#pragma unroll
        for (int k = 0; k < 4; ++k) {
            s += __expf((V[k].x - Cr[r][k].x - m) * INV_EPS);
            s += __expf((V[k].y - Cr[r][k].y - m) * INV_EPS);
            s += __expf((V[k].z - Cr[r][k].z - m) * INV_EPS);
            s += __expf((V[k].w - Cr[r][k].w - m) * INV_EPS);
        }
#pragma unroll
        for (int off = 32; off; off >>= 1) s += __shfl_xor(s, off);
        __syncthreads();  // everyone done reading maxes in red
        if ((t & 63) == 0) red[t >> 6] = s;
        __syncthreads();
        s = red[0] + red[1] + red[2] + red[3];
        __syncthreads();  // red reusable next row
        nv[r] = target - m - EPS * __logf(s);  // uniform across block
    }
    if (t == 0) {
        if (WRITE_ERR) {
            float e = 0.f;
#pragma unroll
            for (int r = 0; r < RPB; ++r) {
                e += fabsf(nv[r] - mine[r0 + r]);
                mine[r0 + r] = nv[r];
            }
            atomicAdd(errslot, e);
        } else {
#pragma unroll
            for (int r = 0; r < RPB; ++r) mine[r0 + r] = nv[r];
        }
    }
}

// ---------------- persistent kernel: all iterations + final, 4 launches total --
__global__ __launch_bounds__(256, 4) void sinkhorn_persist(
    const float* __restrict__ Cm, const float* __restrict__ Ct,
    float* __restrict__ ws, float* __restrict__ out, float target) {
    __shared__ float red[4];
    float* u = ws;
    float* v = ws + N;
    float* errb = ws + WS_ERR;
    const int t = threadIdx.x;
    const int b = blockIdx.x;
    const int r0 = b * RPB;

    for (int it = 0; it < MAX_ITER; ++it) {
        half_step<true>(Cm, v, u, &errb[it], r0, t, target, red);
        grid_sync(ws, b);
        half_step<false>(Ct, u, v, nullptr, r0, t, target, red);
        grid_sync(ws, b);
        // reference latches done=(err<THRESH) AFTER applying this iteration's
        // updates; subsequent iterations are frozen -> break is exact.
        if (errb[it] < THRESH) break;  // uniform: same value in every block
    }

    // ---- final: pi = exp((u_i + v_j - C_ij)/eps), cost = sum(pi*C) ----
    // Ct (aliasing out[0..N^2)) is dead from here on; pi writes may clobber it.
    float* pi = out + 1;
    float4 V[4];
    const float4* vv = (const float4*)v;
#pragma unroll
    for (int k = 0; k < 4; ++k) V[k] = vv[t + 256 * k];
    float csum = 0.f;
#pragma unroll
    for (int r = 0; r < RPB; ++r) {
        const int i = r0 + r;
        const float ui = u[i];
        const float4* crow = (const float4*)(Cm + (size_t)i * N);
        float4* prow = (float4*)(pi + (size_t)i * N);
#pragma unroll
        for (int k = 0; k < 4; ++k) {
            float4 c = crow[t + 256 * k];
            float4 p;
            p.x = __expf((ui + V[k].x - c.x) * INV_EPS);
            p.y = __expf((ui + V[k].y - c.y) * INV_EPS);
            p.z = __expf((ui + V[k].z - c.z) * INV_EPS);
            p.w = __expf((ui + V[k].w - c.w) * INV_EPS);
            prow[t + 256 * k] = p;
            csum = fmaf(p.x, c.x, csum);
            csum = fmaf(p.y, c.y, csum);
            csum = fmaf(p.z, c.z, csum);
            csum = fmaf(p.w, c.w, csum);
        }
    }
#pragma unroll
    for (int off = 32; off; off >>= 1) csum += __shfl_xor(csum, off);
    if ((t & 63) == 0) red[t >> 6] = csum;
    __syncthreads();
    if (t == 0) atomicAdd(ws + WS_COST, red[0] + red[1] + red[2] + red[3]);
    grid_sync(ws, b);
    if (b == 0 && t == 0) out[0] = ws[WS_COST];
}

extern "C" void kernel_launch(void* const* d_in, const int* in_sizes, int n_in,
                              void* d_out, int out_size, void* d_ws, size_t ws_size,
                              hipStream_t stream) {
    const float* x = (const float*)d_in[0];  // [4096,64]
    const float* y = (const float*)d_in[1];  // [4096,64]
    float* out = (float*)d_out;              // [0]=cost, [1..N*N]=pi, [1+N*N..]=C
    float* C = out + 1 + (size_t)N * N;
    float* Ct = out;  // scratch: aliases cost+pi region, dead before final writes
    float* ws = (float*)d_ws;

    init_ws<<<dim3((WS_TOTAL + 255) / 256), dim3(256), 0, stream>>>(ws);

    dim3 bgrid(64, 64);
    build_dist<<<bgrid, dim3(256), 0, stream>>>(x, y, C);   // C[i][j]
    build_dist<<<bgrid, dim3(256), 0, stream>>>(y, x, Ct);  // C^T[j][i]

    float target = EPS * logf(1.0f / (float)N + 1e-8f);  // == eps*log_mu == eps*log_nu

    sinkhorn_persist<<<dim3(NBLK), dim3(256), 0, stream>>>(C, Ct, ws, out, target);
}